// Round 2
// baseline (12996.967 us; speedup 1.0000x reference)
//
#include <hip/hip_runtime.h>
#include <math.h>

// Problem constants
static constexpr int  Bn  = 8;
static constexpr int  Dn  = 1024;
static constexpr int  Ln  = 2048;
static constexpr long DL  = (long)Dn * Ln;   // per-batch x / mlp-out elems
static constexpr long DDm = (long)Dn * Dn;   // per-batch dscore elems
static constexpr long LLm = (long)Ln * Ln;   // per-batch lscore elems
static constexpr long BDL = (long)Bn * DL;
static constexpr long BDD = (long)Bn * DDm;
static constexpr float P_EXP = 1.01005016708416805754f; // exp(0.01)
static constexpr float PI_F  = 3.14159265358979323846f;

// ---------------------------------------------------------------------------
// Generic strided batched GEMM: C[b,m,n] = sum_k A(b,m,k)*B(b,k,n) (+bias[m])
// C is row-major MxN contiguous per batch. Optional epilogue:
//   if addsrc: C = (acc + addsrc[b,m,n]) * 0.5   (final residual/average)
// AKC: A's k-stride is 1 (load tile with k fastest). BNC: B's n-stride is 1.
// Tile 64x64, BK=16, 256 threads, 4x4 acc per thread.
// ---------------------------------------------------------------------------
template<bool AKC, bool BNC>
__global__ __launch_bounds__(256)
void gemm_f32(const float* __restrict__ A, long sAb, long sAm, long sAk,
              const float* __restrict__ Bp, long sBb, long sBk, long sBn,
              float* __restrict__ C, long sCb,
              const float* __restrict__ bias,
              const float* __restrict__ addsrc, long sEb,
              int M, int N, int K)
{
    constexpr int BM = 64, BN = 64, BK = 16;
    __shared__ float As[BK][BM + 1];
    __shared__ float Bs[BK][BN + 1];

    const int tid = threadIdx.x;
    const int tx = tid & 15;      // column group
    const int ty = tid >> 4;      // row group
    const int m0 = blockIdx.y * BM;
    const int n0 = blockIdx.x * BN;
    const int b  = blockIdx.z;

    const float* Ab = A  + (long)b * sAb;
    const float* Bb = Bp + (long)b * sBb;

    float acc[4][4] = {};

    for (int k0 = 0; k0 < K; k0 += BK) {
        if constexpr (AKC) {
            #pragma unroll
            for (int it = 0; it < 4; ++it) {
                int lin = tid + 256 * it;   // m*BK + k
                int m = lin >> 4;
                int k = lin & 15;
                As[k][m] = Ab[(long)(m0 + m) * sAm + (long)(k0 + k) * sAk];
            }
        } else {
            #pragma unroll
            for (int it = 0; it < 4; ++it) {
                int lin = tid + 256 * it;   // k*BM + m
                int k = lin >> 6;
                int m = lin & 63;
                As[k][m] = Ab[(long)(m0 + m) * sAm + (long)(k0 + k) * sAk];
            }
        }
        if constexpr (BNC) {
            #pragma unroll
            for (int it = 0; it < 4; ++it) {
                int lin = tid + 256 * it;   // k*BN + n
                int k = lin >> 6;
                int n = lin & 63;
                Bs[k][n] = Bb[(long)(k0 + k) * sBk + (long)(n0 + n) * sBn];
            }
        } else {
            #pragma unroll
            for (int it = 0; it < 4; ++it) {
                int lin = tid + 256 * it;   // n*BK + k
                int n = lin >> 4;
                int k = lin & 15;
                Bs[k][n] = Bb[(long)(k0 + k) * sBk + (long)(n0 + n) * sBn];
            }
        }
        __syncthreads();

        #pragma unroll
        for (int kk = 0; kk < BK; ++kk) {
            float a[4], bv[4];
            #pragma unroll
            for (int i = 0; i < 4; ++i) a[i] = As[kk][ty + 16 * i];
            #pragma unroll
            for (int j = 0; j < 4; ++j) bv[j] = Bs[kk][tx + 16 * j];
            #pragma unroll
            for (int i = 0; i < 4; ++i)
                #pragma unroll
                for (int j = 0; j < 4; ++j)
                    acc[i][j] = fmaf(a[i], bv[j], acc[i][j]);
        }
        __syncthreads();
    }

    float* Cb = C + (long)b * sCb;
    const float* Eb = addsrc ? addsrc + (long)b * sEb : nullptr;
    #pragma unroll
    for (int i = 0; i < 4; ++i) {
        int m = m0 + ty + 16 * i;
        float bvv = bias ? bias[m] : 0.0f;
        #pragma unroll
        for (int j = 0; j < 4; ++j) {
            int n = n0 + tx + 16 * j;
            float v = acc[i][j] + bvv;
            if (Eb) v = (v + Eb[(long)m * N + n]) * 0.5f;
            Cb[(long)m * N + n] = v;
        }
    }
}

// ---------------------------------------------------------------------------
// Sum of squares over the contiguous last dim: out[row] = sum_c v[row,c]^2
// ---------------------------------------------------------------------------
__global__ __launch_bounds__(256)
void rowsumsq(const float* __restrict__ v, float* __restrict__ out, int ncols)
{
    long row = blockIdx.x;
    const float* p = v + row * (long)ncols;
    float s = 0.f;
    for (int c = threadIdx.x; c < ncols; c += 256) { float t = p[c]; s += t * t; }
    __shared__ float red[256];
    red[threadIdx.x] = s; __syncthreads();
    for (int off = 128; off > 0; off >>= 1) {
        if (threadIdx.x < off) red[threadIdx.x] += red[threadIdx.x + off];
        __syncthreads();
    }
    if (threadIdx.x == 0) out[row] = red[0];
}

// ---------------------------------------------------------------------------
// Sum of squares over the strided (middle) dim: out[b,j] = sum_d v[b,d,j]^2
// ---------------------------------------------------------------------------
__global__ __launch_bounds__(256)
void colsumsq(const float* __restrict__ v, float* __restrict__ out,
              int nrows, int ncols)
{
    int b = blockIdx.y;
    int j = blockIdx.x * 256 + threadIdx.x;
    const float* p = v + (long)b * nrows * ncols + j;
    float s = 0.f;
    for (int d = 0; d < nrows; ++d) { float t = p[(long)d * ncols]; s += t * t; }
    out[(long)b * ncols + j] = s;
}

// ---------------------------------------------------------------------------
// In-place Cauchy map on G:
//   v = relu(0.5 - 0.5*cos(pi*(pow(G^2/(ns[i]*nc[j]), p) - eye)))
// mshift = log2(M). Works on a full (B,M,M) block or a single batch slice
// (pass batch-offset ns/nc pointers; idx>>2*mshift then yields b=0).
// ---------------------------------------------------------------------------
__global__ __launch_bounds__(256)
void cauchy_map(float* __restrict__ G, const float* __restrict__ ns,
                const float* __restrict__ nc, int mshift)
{
    long idx = (long)blockIdx.x * 256 + threadIdx.x;
    int M = 1 << mshift;
    int b = (int)(idx >> (2 * mshift));
    int i = (int)(idx >> mshift) & (M - 1);
    int j = (int)idx & (M - 1);
    float g = G[idx];
    float denom = ns[b * M + i] * nc[b * M + j];
    float ratio = (g * g) / denom;
    float o = powf(ratio, P_EXP) - (i == j ? 1.0f : 0.0f);
    float v = 0.5f - 0.5f * cosf(PI_F * o);
    G[idx] = fmaxf(v, 0.0f);
}

// ---------------------------------------------------------------------------
// Softmax over rows i (axis 1) for each column j of G (B,M,M), in place.
// ---------------------------------------------------------------------------
__global__ __launch_bounds__(256)
void softmax_col(float* __restrict__ G, int M)
{
    int b = blockIdx.y;
    int j = blockIdx.x * 256 + threadIdx.x;
    float* p = G + (long)b * M * M + j;
    float vmax = -1e30f;
    for (int i = 0; i < M; ++i) vmax = fmaxf(vmax, p[(long)i * M]);
    float s = 0.f;
    for (int i = 0; i < M; ++i) s += __expf(p[(long)i * M] - vmax);
    float inv = 1.0f / s;
    for (int i = 0; i < M; ++i) {
        float e = __expf(p[(long)i * M] - vmax);
        p[(long)i * M] = e * inv;
    }
}

// ---------------------------------------------------------------------------
// Softmax over the contiguous last dim of G (rows × M), in place.
// One block per row; grid.x = number of rows.
// ---------------------------------------------------------------------------
__global__ __launch_bounds__(256)
void softmax_row(float* __restrict__ G, int M)
{
    long row = blockIdx.x;
    float* p = G + row * (long)M;
    __shared__ float red[256];

    float lmax = -1e30f;
    for (int c = threadIdx.x; c < M; c += 256) lmax = fmaxf(lmax, p[c]);
    red[threadIdx.x] = lmax; __syncthreads();
    for (int off = 128; off > 0; off >>= 1) {
        if (threadIdx.x < off) red[threadIdx.x] = fmaxf(red[threadIdx.x], red[threadIdx.x + off]);
        __syncthreads();
    }
    float vmax = red[0]; __syncthreads();

    float s = 0.f;
    for (int c = threadIdx.x; c < M; c += 256) s += __expf(p[c] - vmax);
    red[threadIdx.x] = s; __syncthreads();
    for (int off = 128; off > 0; off >>= 1) {
        if (threadIdx.x < off) red[threadIdx.x] += red[threadIdx.x + off];
        __syncthreads();
    }
    float inv = 1.0f / red[0];
    for (int c = threadIdx.x; c < M; c += 256) p[c] = __expf(p[c] - vmax) * inv;
}

// ---------------------------------------------------------------------------
// Host-side GEMM dispatch (nb = batch count in grid.z)
// ---------------------------------------------------------------------------
static void launch_gemm(hipStream_t stream, bool akc, bool bnc,
                        const float* A, long sAb, long sAm, long sAk,
                        const float* B, long sBb, long sBk, long sBn,
                        float* C, long sCb,
                        const float* bias,
                        const float* addsrc, long sEb,
                        int M, int N, int K, int nb)
{
    dim3 grid(N / 64, M / 64, nb);
    dim3 blk(256);
    if (akc) {
        if (bnc) gemm_f32<true, true><<<grid, blk, 0, stream>>>(A, sAb, sAm, sAk, B, sBb, sBk, sBn, C, sCb, bias, addsrc, sEb, M, N, K);
        else     gemm_f32<true, false><<<grid, blk, 0, stream>>>(A, sAb, sAm, sAk, B, sBb, sBk, sBn, C, sCb, bias, addsrc, sEb, M, N, K);
    } else {
        if (bnc) gemm_f32<false, true><<<grid, blk, 0, stream>>>(A, sAb, sAm, sAk, B, sBb, sBk, sBn, C, sCb, bias, addsrc, sEb, M, N, K);
        else     gemm_f32<false, false><<<grid, blk, 0, stream>>>(A, sAb, sAm, sAk, B, sBb, sBk, sBn, C, sCb, bias, addsrc, sEb, M, N, K);
    }
}

// 3-layer pointwise MLP: dst = L3(L2(L1(x))). Ping-pong: x -> dst -> scratch -> dst.
static void launch_mlp(hipStream_t stream, const float* x, const float* W,
                       const float* bias, float* dst, float* scratch)
{
    const float* in = x;
    float* outs[3] = { dst, scratch, dst };
    for (int l = 0; l < 3; ++l) {
        launch_gemm(stream, /*akc=*/true, /*bnc=*/true,
                    W + (long)l * DDm, 0, Dn, 1,          // A = W[l] (D,D) row-major
                    in, DL, Ln, 1,                        // B = activations (D,L)
                    outs[l], DL,
                    bias + (long)l * Dn,
                    nullptr, 0,
                    Dn, Ln, Dn, Bn);
        in = outs[l];
    }
}

extern "C" void kernel_launch(void* const* d_in, const int* in_sizes, int n_in,
                              void* d_out, int out_size, void* d_ws, size_t ws_size,
                              hipStream_t stream)
{
    const float* x  = (const float*)d_in[0];
    const float* W1 = (const float*)d_in[1]; const float* b1 = (const float*)d_in[2];
    const float* W2 = (const float*)d_in[3]; const float* b2 = (const float*)d_in[4];
    const float* W3 = (const float*)d_in[5]; const float* b3 = (const float*)d_in[6];
    const float* W4 = (const float*)d_in[7]; const float* b4 = (const float*)d_in[8];
    float* out = (float*)d_out;

    // Workspace carve-up (floats), ~184 MB total:
    //   a1 (BDL) | a2 (BDL) | Gd (BDD) | Glb (LLm, per-batch) | tb (DL, per-batch) | norms
    // d_out doubles as the MLP ping-pong scratch (free until the final GEMM).
    float* ws   = (float*)d_ws;
    float* a1   = ws;
    float* a2   = a1 + BDL;
    float* Gd   = a2 + BDL;
    float* Glb  = Gd + BDD;
    float* tb   = Glb + LLm;
    float* ns_d = tb + DL;
    float* nc_d = ns_d + (long)Bn * Dn;
    float* ns_l = nc_d + (long)Bn * Dn;
    float* nc_l = ns_l + (long)Bn * Ln;

    float* scratch = out;   // MLP intermediate; fully overwritten at the end

    // --- channel-mixing branch ---
    launch_mlp(stream, x, W1, b1, a1, scratch);   // dsx
    launch_mlp(stream, x, W2, b2, a2, scratch);   // dcx

    rowsumsq<<<dim3(Bn * Dn), dim3(256), 0, stream>>>(a1, ns_d, Ln);
    rowsumsq<<<dim3(Bn * Dn), dim3(256), 0, stream>>>(a2, nc_d, Ln);

    // Gd = dsx @ dcx^T : (D,L)x(L,D) NT, full batch (32 MB)
    launch_gemm(stream, true, false,
                a1, DL, Ln, 1,
                a2, DL, 1, Ln,
                Gd, DDm, nullptr, nullptr, 0,
                Dn, Dn, Ln, Bn);
    cauchy_map<<<dim3((unsigned)(BDD / 256)), dim3(256), 0, stream>>>(Gd, ns_d, nc_d, 10);
    softmax_col<<<dim3(Dn / 256, Bn), dim3(256), 0, stream>>>(Gd, Dn);

    // --- token-mixing branch (reuse a1/a2) ---
    launch_mlp(stream, x, W3, b3, a1, scratch);   // lsx
    launch_mlp(stream, x, W4, b4, a2, scratch);   // lcx

    colsumsq<<<dim3(Ln / 256, Bn), dim3(256), 0, stream>>>(a1, ns_l, Dn, Ln);
    colsumsq<<<dim3(Ln / 256, Bn), dim3(256), 0, stream>>>(a2, nc_l, Dn, Ln);

    // Per-batch: Gl_b (16 MB) -> softmax -> t_b -> out_b. Keeps peak ws low.
    for (int b = 0; b < Bn; ++b) {
        const float* lsxb = a1 + (long)b * DL;
        const float* lcxb = a2 + (long)b * DL;

        // Gl_b = lsx_b^T @ lcx_b : (L,D)x(D,L) TN
        launch_gemm(stream, false, true,
                    lsxb, 0, 1, Ln,
                    lcxb, 0, Ln, 1,
                    Glb, 0, nullptr, nullptr, 0,
                    Ln, Ln, Dn, 1);
        cauchy_map<<<dim3((unsigned)(LLm / 256)), dim3(256), 0, stream>>>(
            Glb, ns_l + (long)b * Ln, nc_l + (long)b * Ln, 11);
        softmax_row<<<dim3(Ln), dim3(256), 0, stream>>>(Glb, Ln);

        // t_b = dscore_b @ x_b : (D,D)x(D,L)
        launch_gemm(stream, true, true,
                    Gd + (long)b * DDm, 0, Dn, 1,
                    x + (long)b * DL, 0, Ln, 1,
                    tb, 0, nullptr, nullptr, 0,
                    Dn, Ln, Dn, 1);
        // out_b = (t_b @ Gl_b + x_b) / 2 : (D,L)x(L,L)
        launch_gemm(stream, true, true,
                    tb, 0, Ln, 1,
                    Glb, 0, Ln, 1,
                    out + (long)b * DL, 0, nullptr, x + (long)b * DL, 0,
                    Dn, Ln, Ln, 1);
    }
}

// Round 3
// 2548.778 us; speedup vs baseline: 5.0993x; 5.0993x over previous
//
#include <hip/hip_runtime.h>
#include <hip/hip_bf16.h>
#include <math.h>

// Problem constants
static constexpr int  Bn = 8, Dn = 1024, Ln = 2048;
static constexpr long DL  = (long)Dn * Ln;
static constexpr long DDm = (long)Dn * Dn;
static constexpr long LLm = (long)Ln * Ln;
static constexpr long BDL = (long)Bn * DL;
static constexpr float P_EXP = 1.01005016708416805754f; // exp(0.01)
static constexpr float PI_F  = 3.14159265358979323846f;

using bf = __hip_bfloat16;
typedef short s16x8 __attribute__((ext_vector_type(8)));   // 8 bf16 = 4 VGPRs (MFMA A/B frag)
typedef float f32x4 __attribute__((ext_vector_type(4)));   // MFMA C/D frag

#define GPTR(x) ((const __attribute__((address_space(1))) void*)(x))
#define LPTR(x) ((__attribute__((address_space(3))) void*)(x))

enum { EPI_BIAS = 0, EPI_PLAIN = 1, EPI_CAUCHY = 2, EPI_RESID = 3 };

// ---------------------------------------------------------------------------
// NT bf16 MFMA GEMM: C[b,m,n] = sum_k A[b,m,k] * Bt[b,n,k]   (both k-contig)
// 128x128 tile, BK=32, 256 threads (4 waves, 2x2 of 64x64 wave tiles),
// global_load_lds width-16 staging, swizzled LDS k-chunks.
// Epilogues: BIAS   -> bf16 C = acc + bias[n]
//            PLAIN  -> bf16 C = acc
//            CAUCHY -> f32  C = relu(0.5-0.5*cos(pi*(pow(acc^2/(rowN[m]*colN[n]),p)-eye)))
//            RESID  -> f32  C = (acc + resid[m,n]) * 0.5
// ---------------------------------------------------------------------------
template<int EPI>
__global__ __launch_bounds__(256)
void gemm_nt(const short* __restrict__ A, long sAb, int ldA,
             const short* __restrict__ Bt, long sBb, int ldB,
             void* __restrict__ Cv, long sCb, int ldC,
             const float* __restrict__ bias,
             const float* __restrict__ rowN, const float* __restrict__ colN,
             const float* __restrict__ resid, long sRb,
             int M, int N, int K)
{
    __shared__ short As[128 * 32];   // row-major, 32 bf16 per row, k-chunk swizzled
    __shared__ short Bs[128 * 32];

    const int tid  = threadIdx.x;
    const int lane = tid & 63;
    const int w    = tid >> 6;           // wave 0..3
    const int wm   = w >> 1, wn = w & 1; // 2x2 wave grid
    const int m0   = blockIdx.y * 128;
    const int n0   = blockIdx.x * 128;
    const int bz   = blockIdx.z;

    const short* Ab = A  + (long)bz * sAb;
    const short* Bb = Bt + (long)bz * sBb;

    const int srow = lane >> 2;                                  // 0..15 row within 16-row chunk
    const int kc   = ((lane & 3) + 4 - ((lane >> 3) & 3)) & 3;   // swizzled global k-chunk
    const int quad = lane >> 4;
    const int l15  = lane & 15;

    // LDS read offsets (shorts) for the 4 A / 4 B fragments
    int aoff[4], boff[4];
    #pragma unroll
    for (int i = 0; i < 4; ++i) {
        int rA = wm * 64 + i * 16 + l15;
        aoff[i] = rA * 32 + (((quad + (rA >> 1)) & 3) << 3);
        int rB = wn * 64 + i * 16 + l15;
        boff[i] = rB * 32 + (((quad + (rB >> 1)) & 3) << 3);
    }

    // staging: wave w owns 1KB chunks {2w, 2w+1} of both A and B tiles
    const int  ca0 = 2 * w;
    const long gA0 = (long)(m0 + ca0 * 16 + srow)       * ldA + kc * 8;
    const long gA1 = (long)(m0 + (ca0 + 1) * 16 + srow) * ldA + kc * 8;
    const long gB0 = (long)(n0 + ca0 * 16 + srow)       * ldB + kc * 8;
    const long gB1 = (long)(n0 + (ca0 + 1) * 16 + srow) * ldB + kc * 8;
    short* lA0 = As + ca0 * 512;
    short* lA1 = As + ca0 * 512 + 512;
    short* lB0 = Bs + ca0 * 512;
    short* lB1 = Bs + ca0 * 512 + 512;

    f32x4 acc[4][4] = {};

    for (int k0 = 0; k0 < K; k0 += 32) {
        __builtin_amdgcn_global_load_lds(GPTR(Ab + gA0 + k0), LPTR(lA0), 16, 0, 0);
        __builtin_amdgcn_global_load_lds(GPTR(Ab + gA1 + k0), LPTR(lA1), 16, 0, 0);
        __builtin_amdgcn_global_load_lds(GPTR(Bb + gB0 + k0), LPTR(lB0), 16, 0, 0);
        __builtin_amdgcn_global_load_lds(GPTR(Bb + gB1 + k0), LPTR(lB1), 16, 0, 0);
        __syncthreads();

        s16x8 af[4], bfr[4];
        #pragma unroll
        for (int i = 0; i < 4; ++i) af[i]  = *(const s16x8*)(As + aoff[i]);
        #pragma unroll
        for (int j = 0; j < 4; ++j) bfr[j] = *(const s16x8*)(Bs + boff[j]);
        #pragma unroll
        for (int i = 0; i < 4; ++i)
            #pragma unroll
            for (int j = 0; j < 4; ++j)
                acc[i][j] = __builtin_amdgcn_mfma_f32_16x16x32_bf16(af[i], bfr[j], acc[i][j], 0, 0, 0);
        __syncthreads();
    }

    // Epilogue. C/D layout: col = lane&15, row = quad*4 + r within each 16x16.
    if constexpr (EPI == EPI_BIAS || EPI == EPI_PLAIN) {
        bf* C = (bf*)Cv + (long)bz * sCb;
        #pragma unroll
        for (int j = 0; j < 4; ++j) {
            int n = n0 + wn * 64 + j * 16 + l15;
            float bv = (EPI == EPI_BIAS) ? bias[n] : 0.f;
            #pragma unroll
            for (int i = 0; i < 4; ++i) {
                int mb = m0 + wm * 64 + i * 16 + quad * 4;
                #pragma unroll
                for (int r = 0; r < 4; ++r)
                    C[(long)(mb + r) * ldC + n] = __float2bfloat16(acc[i][j][r] + bv);
            }
        }
    } else if constexpr (EPI == EPI_CAUCHY) {
        float* C = (float*)Cv + (long)bz * sCb;
        const float* rN = rowN + (long)bz * M;
        const float* cN = colN + (long)bz * N;
        #pragma unroll
        for (int j = 0; j < 4; ++j) {
            int n = n0 + wn * 64 + j * 16 + l15;
            float cn = cN[n];
            #pragma unroll
            for (int i = 0; i < 4; ++i) {
                int mb = m0 + wm * 64 + i * 16 + quad * 4;
                #pragma unroll
                for (int r = 0; r < 4; ++r) {
                    int m = mb + r;
                    float g = acc[i][j][r];
                    float ratio = (g * g) / (rN[m] * cn);
                    float o = __powf(ratio, P_EXP) - ((m == n) ? 1.f : 0.f);
                    float v = 0.5f - 0.5f * __cosf(PI_F * o);
                    C[(long)m * ldC + n] = fmaxf(v, 0.f);
                }
            }
        }
    } else { // EPI_RESID
        float* C = (float*)Cv + (long)bz * sCb;
        const float* Rs = resid + (long)bz * sRb;
        #pragma unroll
        for (int j = 0; j < 4; ++j) {
            int n = n0 + wn * 64 + j * 16 + l15;
            #pragma unroll
            for (int i = 0; i < 4; ++i) {
                int mb = m0 + wm * 64 + i * 16 + quad * 4;
                #pragma unroll
                for (int r = 0; r < 4; ++r) {
                    int m = mb + r;
                    C[(long)m * ldC + n] = (acc[i][j][r] + Rs[(long)m * ldC + n]) * 0.5f;
                }
            }
        }
    }
}

// ---------------------------------------------------------------------------
// Transpose-cast: in (nb, R, C) [TI = float or bf16] -> out (nb, C, R) bf16.
// ---------------------------------------------------------------------------
template<typename TI>
__global__ __launch_bounds__(256)
void transpose_cast(const TI* __restrict__ in, bf* __restrict__ outp, int R, int C)
{
    __shared__ float tile[32][33];
    long base = (long)blockIdx.z * R * C;
    int r0 = blockIdx.y * 32, c0 = blockIdx.x * 32;
    int tx = threadIdx.x & 31, ty = threadIdx.x >> 5;
    #pragma unroll
    for (int i = 0; i < 4; ++i)
        tile[ty + 8 * i][tx] = (float)in[base + (long)(r0 + ty + 8 * i) * C + c0 + tx];
    __syncthreads();
    #pragma unroll
    for (int i = 0; i < 4; ++i)
        outp[base + (long)(c0 + ty + 8 * i) * R + r0 + tx] = __float2bfloat16(tile[tx][ty + 8 * i]);
}

// Flat fp32 -> bf16 cast
__global__ __launch_bounds__(256)
void cast_bf(const float* __restrict__ in, bf* __restrict__ outp, long n)
{
    long i = (long)blockIdx.x * 256 + threadIdx.x;
    if (i < n) outp[i] = __float2bfloat16(in[i]);
}

// Row sum-of-squares over contiguous last dim (bf16 in, fp32 out)
__global__ __launch_bounds__(256)
void rowsumsq(const bf* __restrict__ v, float* __restrict__ outp, int ncols)
{
    long row = blockIdx.x;
    const bf* p = v + row * (long)ncols;
    float s = 0.f;
    for (int c = threadIdx.x; c < ncols; c += 256) { float t = (float)p[c]; s += t * t; }
    __shared__ float red[256];
    red[threadIdx.x] = s; __syncthreads();
    for (int off = 128; off > 0; off >>= 1) {
        if (threadIdx.x < off) red[threadIdx.x] += red[threadIdx.x + off];
        __syncthreads();
    }
    if (threadIdx.x == 0) outp[row] = red[0];
}

// matvec: out[o] = sum_i W[o][i]*v[i] + c[o]   (fp32, tiny)
__global__ __launch_bounds__(256)
void matvec_bias(const float* __restrict__ W, const float* __restrict__ v,
                 const float* __restrict__ c, float* __restrict__ outp, int n)
{
    int o = blockIdx.x;
    const float* row = W + (long)o * n;
    float s = 0.f;
    for (int i = threadIdx.x; i < n; i += 256) s += row[i] * v[i];
    __shared__ float red[256];
    red[threadIdx.x] = s; __syncthreads();
    for (int off = 128; off > 0; off >>= 1) {
        if (threadIdx.x < off) red[threadIdx.x] += red[threadIdx.x + off];
        __syncthreads();
    }
    if (threadIdx.x == 0) outp[o] = red[0] + c[o];
}

// Column softmax of G (nb, M, M) fp32 -> bf16 out. Block = 32 cols x 8 slices.
__global__ __launch_bounds__(256)
void softmax_col_bf16(const float* __restrict__ G, bf* __restrict__ outp, int M)
{
    int bz = blockIdx.y;
    int c  = threadIdx.x & 31;
    int sl = threadIdx.x >> 5;     // 0..7
    int j  = blockIdx.x * 32 + c;
    const float* p = G + (long)bz * M * M + j;
    bf* q = outp + (long)bz * M * M + j;
    int chunk = M >> 3;
    int i0 = sl * chunk, i1 = i0 + chunk;
    __shared__ float red[8][33];

    float vmax = -3.4e38f;
    for (int i = i0; i < i1; ++i) vmax = fmaxf(vmax, p[(long)i * M]);
    red[sl][c] = vmax; __syncthreads();
    if (sl == 0) {
        float m2 = red[0][c];
        #pragma unroll
        for (int s = 1; s < 8; ++s) m2 = fmaxf(m2, red[s][c]);
        red[0][c] = m2;
    }
    __syncthreads();
    float mm = red[0][c];
    __syncthreads();

    float ssum = 0.f;
    for (int i = i0; i < i1; ++i) ssum += __expf(p[(long)i * M] - mm);
    red[sl][c] = ssum; __syncthreads();
    if (sl == 0) {
        float s2 = 0.f;
        #pragma unroll
        for (int s = 0; s < 8; ++s) s2 += red[s][c];
        red[0][c] = s2;
    }
    __syncthreads();
    float inv = 1.f / red[0][c];
    for (int i = i0; i < i1; ++i)
        q[(long)i * M] = __float2bfloat16(__expf(p[(long)i * M] - mm) * inv);
}

// ---------------------------------------------------------------------------
// Host-side GEMM dispatch
// ---------------------------------------------------------------------------
static void glaunch(hipStream_t st, int epi,
                    const bf* A, long sAb, int ldA,
                    const bf* Bt, long sBb, int ldB,
                    void* C, long sCb, int ldC,
                    const float* bias, const float* rowN, const float* colN,
                    const float* resid, long sRb,
                    int M, int N, int K, int nb)
{
    dim3 g(N / 128, M / 128, nb), blk(256);
    const short* As = (const short*)A;
    const short* Bs = (const short*)Bt;
    switch (epi) {
    case EPI_BIAS:   gemm_nt<EPI_BIAS>  <<<g, blk, 0, st>>>(As, sAb, ldA, Bs, sBb, ldB, C, sCb, ldC, bias, rowN, colN, resid, sRb, M, N, K); break;
    case EPI_PLAIN:  gemm_nt<EPI_PLAIN> <<<g, blk, 0, st>>>(As, sAb, ldA, Bs, sBb, ldB, C, sCb, ldC, bias, rowN, colN, resid, sRb, M, N, K); break;
    case EPI_CAUCHY: gemm_nt<EPI_CAUCHY><<<g, blk, 0, st>>>(As, sAb, ldA, Bs, sBb, ldB, C, sCb, ldC, bias, rowN, colN, resid, sRb, M, N, K); break;
    default:         gemm_nt<EPI_RESID> <<<g, blk, 0, st>>>(As, sAb, ldA, Bs, sBb, ldB, C, sCb, ldC, bias, rowN, colN, resid, sRb, M, N, K); break;
    }
}

extern "C" void kernel_launch(void* const* d_in, const int* in_sizes, int n_in,
                              void* d_out, int out_size, void* d_ws, size_t ws_size,
                              hipStream_t stream)
{
    const float* x = (const float*)d_in[0];
    float* out = (float*)d_out;

    // Arena (bytes). Total 184,766,464 (< 193 MB proven safe in round 1).
    uint8_t* wsb = (uint8_t*)d_ws;
    if (ws_size < 184766464u) return;  // fail loudly (wrong output), not by OOB fault

    bf*    x_t    = (bf*)(wsb + 0);              // (B,L,D) bf16        33,554,432
    bf*    dscore = (bf*)(wsb + 33554432);       // (B,D,D) bf16        16,777,216
    bf*    Weff   = (bf*)(wsb + 50331648);       // 4 x (D,D) bf16       8,388,608
    float* beff   = (float*)(wsb + 58720256);    // 4 x D fp32              16,384
    float* b01    = (float*)(wsb + 58736640);    // D fp32                   4,096
    float* ns_d   = (float*)(wsb + 58740736);    // norms: 196,608 total
    float* nc_d   = ns_d + (long)Bn * Dn;
    float* ns_l   = nc_d + (long)Bn * Dn;
    float* nc_l   = ns_l + (long)Bn * Ln;
    uint8_t* R0   = wsb + 58937344;              // 25,165,824 reuse region
    bf*    S0     = (bf*)(wsb + 84103168);       // 33,554,432 each
    bf*    S1     = (bf*)(wsb + 117657600);
    bf*    S2     = (bf*)(wsb + 151212032);

    // R0 sub-layouts (time-disjoint uses)
    bf* W0t  = (bf*)R0;             // compose phase
    bf* W1b  = W0t + DDm;
    bf* W2b  = W1b + DDm;
    bf* Zb   = W2b + DDm;
    bf* Zt   = Zb + DDm;
    bf* lsc2 = (bf*)R0;             // apply phase: 2*LLm bf16 = 16,777,216
    bf* t1_2 = (bf*)(R0 + 16777216);//              2*DL  bf16 =  8,388,608

    // ---- x transpose-cast: (B,D,L) f32 -> (B,L,D) bf16 ----
    transpose_cast<float><<<dim3(Ln / 32, Dn / 32, Bn), 256, 0, stream>>>(x, x_t, Dn, Ln);

    // ---- collapse each 3-layer linear MLP: Weff = W2*W1*W0, beff = W2*(W1*b0+b1)+b2 ----
    for (int k = 0; k < 4; ++k) {
        const float* Wk = (const float*)d_in[1 + 2 * k];
        const float* bk = (const float*)d_in[2 + 2 * k];
        cast_bf<<<dim3((unsigned)(DDm / 256)), 256, 0, stream>>>(Wk + DDm,     W1b, DDm);
        cast_bf<<<dim3((unsigned)(DDm / 256)), 256, 0, stream>>>(Wk + 2 * DDm, W2b, DDm);
        transpose_cast<float><<<dim3(Dn / 32, Dn / 32, 1), 256, 0, stream>>>(Wk, W0t, Dn, Dn);
        // Z = W1*W0 : NT(A=W1b, Bt=W0t)
        glaunch(stream, EPI_PLAIN, W1b, 0, Dn, W0t, 0, Dn, Zb, 0, Dn,
                nullptr, nullptr, nullptr, nullptr, 0, Dn, Dn, Dn, 1);
        transpose_cast<bf><<<dim3(Dn / 32, Dn / 32, 1), 256, 0, stream>>>(Zb, Zt, Dn, Dn);
        // Weff_k = W2*Z : NT(A=W2b, Bt=Zt)
        glaunch(stream, EPI_PLAIN, W2b, 0, Dn, Zt, 0, Dn, Weff + (long)k * DDm, 0, Dn,
                nullptr, nullptr, nullptr, nullptr, 0, Dn, Dn, Dn, 1);
        matvec_bias<<<dim3(Dn), 256, 0, stream>>>(Wk + DDm,     bk,          bk + Dn,     b01,               Dn);
        matvec_bias<<<dim3(Dn), 256, 0, stream>>>(Wk + 2 * DDm, b01,         bk + 2 * Dn, beff + (long)k * Dn, Dn);
    }

    // ---- channel branch ----
    // dsx_t = x_t @ Weff1^T + beff1 : (B,L,D) bf16 @ S1
    glaunch(stream, EPI_BIAS, x_t, DL, Dn, Weff, 0, Dn, S1, DL, Dn,
            beff, nullptr, nullptr, nullptr, 0, Ln, Dn, Dn, Bn);
    transpose_cast<bf><<<dim3(Dn / 32, Ln / 32, Bn), 256, 0, stream>>>(S1, S0, Ln, Dn); // dsx (B,D,L) @ S0
    glaunch(stream, EPI_BIAS, x_t, DL, Dn, Weff + DDm, 0, Dn, S1, DL, Dn,
            beff + Dn, nullptr, nullptr, nullptr, 0, Ln, Dn, Dn, Bn);
    transpose_cast<bf><<<dim3(Dn / 32, Ln / 32, Bn), 256, 0, stream>>>(S1, S2, Ln, Dn); // dcx (B,D,L) @ S2

    rowsumsq<<<dim3(Bn * Dn), 256, 0, stream>>>(S0, ns_d, Ln);
    rowsumsq<<<dim3(Bn * Dn), 256, 0, stream>>>(S2, nc_d, Ln);

    // Gd = cauchy(dsx @ dcx^T) fp32 @ S1
    glaunch(stream, EPI_CAUCHY, S0, DL, Ln, S2, DL, Ln, (float*)S1, DDm, Dn,
            nullptr, ns_d, nc_d, nullptr, 0, Dn, Dn, Ln, Bn);
    softmax_col_bf16<<<dim3(Dn / 32, Bn), 256, 0, stream>>>((float*)S1, dscore, Dn);

    // ---- token branch ----
    glaunch(stream, EPI_BIAS, x_t, DL, Dn, Weff + 2 * DDm, 0, Dn, S0, DL, Dn,
            beff + 2 * Dn, nullptr, nullptr, nullptr, 0, Ln, Dn, Dn, Bn);       // lsx_t @ S0
    glaunch(stream, EPI_BIAS, x_t, DL, Dn, Weff + 3 * DDm, 0, Dn, S2, DL, Dn,
            beff + 3 * Dn, nullptr, nullptr, nullptr, 0, Ln, Dn, Dn, Bn);       // lcx_t @ S2

    rowsumsq<<<dim3(Bn * Ln), 256, 0, stream>>>(S0, ns_l, Dn);
    rowsumsq<<<dim3(Bn * Ln), 256, 0, stream>>>(S2, nc_l, Dn);

    // ---- token score + apply, in batch pairs ----
    for (int pb = 0; pb < 4; ++pb) {
        long bo = 2L * pb;
        // Glt (= Gl^T) = cauchy(lcx_t @ lsx_t^T) fp32 @ S1, 2 batches.
        // rowN indexed by m=j -> nc_l ; colN indexed by n=i -> ns_l.
        glaunch(stream, EPI_CAUCHY, S2 + bo * DL, DL, Dn, S0 + bo * DL, DL, Dn,
                (float*)S1, LLm, Ln,
                nullptr, nc_l + bo * Ln, ns_l + bo * Ln, nullptr, 0, Ln, Ln, Dn, 2);
        // softmax over original axis 2 == column softmax of Glt; bf16 out = Bt operand of final GEMM
        softmax_col_bf16<<<dim3(Ln / 32, 2), 256, 0, stream>>>((float*)S1, lsc2, Ln);
        // t1 = dscore @ x : NT(A=dscore, Bt=x_t) -> bf16 (D,L)
        glaunch(stream, EPI_PLAIN, dscore + bo * DDm, DDm, Dn, x_t + bo * DL, DL, Dn,
                t1_2, DL, Ln, nullptr, nullptr, nullptr, nullptr, 0, Dn, Ln, Dn, 2);
        // out = (t1 @ lscore + x) / 2 : NT(A=t1, Bt=lsc) fp32
        glaunch(stream, EPI_RESID, t1_2, DL, Ln, lsc2, LLm, Ln,
                out + bo * DL, DL, Ln, nullptr, nullptr, nullptr, x + bo * DL, DL,
                Dn, Ln, Ln, 2);
    }
}

// Round 4
// 1512.521 us; speedup vs baseline: 8.5929x; 1.6851x over previous
//
#include <hip/hip_runtime.h>
#include <hip/hip_bf16.h>
#include <math.h>

// Problem constants
static constexpr int  Bn = 8, Dn = 1024, Ln = 2048;
static constexpr long DL  = (long)Dn * Ln;
static constexpr long DDm = (long)Dn * Dn;
static constexpr long LLm = (long)Ln * Ln;
static constexpr float P_EXP = 1.01005016708416805754f; // exp(0.01)
static constexpr float PI_F  = 3.14159265358979323846f;

using bf = __hip_bfloat16;
typedef short s16x8 __attribute__((ext_vector_type(8)));   // 8 bf16 = 4 VGPRs (MFMA A/B frag)
typedef float f32x4 __attribute__((ext_vector_type(4)));   // MFMA C/D frag

#define GPTR(x) ((const __attribute__((address_space(1))) void*)(x))
#define LPTR(x) ((__attribute__((address_space(3))) void*)(x))

enum { EPI_BIAS = 0, EPI_PLAIN = 1, EPI_CAUCHY = 2, EPI_RESID = 3, EPI_BIASM = 4 };

// ---------------------------------------------------------------------------
// NT bf16 MFMA GEMM: C[b,m,n] = sum_k A[b,m,k] * Bt[b,n,k]   (both k-contig)
// 128x128 tile, BK=32, 256 threads (4 waves, 2x2 of 64x64 wave tiles),
// global_load_lds width-16 staging, swizzled LDS k-chunks.
// Epilogues: BIAS   -> bf16 C = acc + bias[n]
//            BIASM  -> bf16 C = acc + bias[m]
//            PLAIN  -> bf16 C = acc
//            CAUCHY -> f32  C = relu(0.5-0.5*cos(pi*(pow(acc^2/(rowN[m]*colN[n]),p)-eye)))
//            RESID  -> f32  C = (acc + resid[m,n]) * 0.5
// ---------------------------------------------------------------------------
template<int EPI>
__global__ __launch_bounds__(256)
void gemm_nt(const short* __restrict__ A, long sAb, int ldA,
             const short* __restrict__ Bt, long sBb, int ldB,
             void* __restrict__ Cv, long sCb, int ldC,
             const float* __restrict__ bias,
             const float* __restrict__ rowN, const float* __restrict__ colN,
             const float* __restrict__ resid, long sRb,
             int M, int N, int K)
{
    __shared__ short As[128 * 32];   // row-major, 32 bf16 per row, k-chunk swizzled
    __shared__ short Bs[128 * 32];

    const int tid  = threadIdx.x;
    const int lane = tid & 63;
    const int w    = tid >> 6;           // wave 0..3
    const int wm   = w >> 1, wn = w & 1; // 2x2 wave grid
    const int m0   = blockIdx.y * 128;
    const int n0   = blockIdx.x * 128;
    const int bz   = blockIdx.z;

    const short* Ab = A  + (long)bz * sAb;
    const short* Bb = Bt + (long)bz * sBb;

    const int srow = lane >> 2;                                  // 0..15 row within 16-row chunk
    const int kc   = ((lane & 3) + 4 - ((lane >> 3) & 3)) & 3;   // swizzled global k-chunk
    const int quad = lane >> 4;
    const int l15  = lane & 15;

    // LDS read offsets (shorts) for the 4 A / 4 B fragments
    int aoff[4], boff[4];
    #pragma unroll
    for (int i = 0; i < 4; ++i) {
        int rA = wm * 64 + i * 16 + l15;
        aoff[i] = rA * 32 + (((quad + (rA >> 1)) & 3) << 3);
        int rB = wn * 64 + i * 16 + l15;
        boff[i] = rB * 32 + (((quad + (rB >> 1)) & 3) << 3);
    }

    // staging: wave w owns 1KB chunks {2w, 2w+1} of both A and B tiles
    const int  ca0 = 2 * w;
    const long gA0 = (long)(m0 + ca0 * 16 + srow)       * ldA + kc * 8;
    const long gA1 = (long)(m0 + (ca0 + 1) * 16 + srow) * ldA + kc * 8;
    const long gB0 = (long)(n0 + ca0 * 16 + srow)       * ldB + kc * 8;
    const long gB1 = (long)(n0 + (ca0 + 1) * 16 + srow) * ldB + kc * 8;
    short* lA0 = As + ca0 * 512;
    short* lA1 = As + ca0 * 512 + 512;
    short* lB0 = Bs + ca0 * 512;
    short* lB1 = Bs + ca0 * 512 + 512;

    f32x4 acc[4][4] = {};

    for (int k0 = 0; k0 < K; k0 += 32) {
        __builtin_amdgcn_global_load_lds(GPTR(Ab + gA0 + k0), LPTR(lA0), 16, 0, 0);
        __builtin_amdgcn_global_load_lds(GPTR(Ab + gA1 + k0), LPTR(lA1), 16, 0, 0);
        __builtin_amdgcn_global_load_lds(GPTR(Bb + gB0 + k0), LPTR(lB0), 16, 0, 0);
        __builtin_amdgcn_global_load_lds(GPTR(Bb + gB1 + k0), LPTR(lB1), 16, 0, 0);
        __syncthreads();

        s16x8 af[4], bfr[4];
        #pragma unroll
        for (int i = 0; i < 4; ++i) af[i]  = *(const s16x8*)(As + aoff[i]);
        #pragma unroll
        for (int j = 0; j < 4; ++j) bfr[j] = *(const s16x8*)(Bs + boff[j]);
        #pragma unroll
        for (int i = 0; i < 4; ++i)
            #pragma unroll
            for (int j = 0; j < 4; ++j)
                acc[i][j] = __builtin_amdgcn_mfma_f32_16x16x32_bf16(af[i], bfr[j], acc[i][j], 0, 0, 0);
        __syncthreads();
    }

    // Epilogue. C/D layout: col = lane&15, row = quad*4 + r within each 16x16.
    if constexpr (EPI == EPI_BIAS || EPI == EPI_PLAIN || EPI == EPI_BIASM) {
        bf* C = (bf*)Cv + (long)bz * sCb;
        #pragma unroll
        for (int j = 0; j < 4; ++j) {
            int n = n0 + wn * 64 + j * 16 + l15;
            float bv = (EPI == EPI_BIAS) ? bias[n] : 0.f;
            #pragma unroll
            for (int i = 0; i < 4; ++i) {
                int mb = m0 + wm * 64 + i * 16 + quad * 4;
                #pragma unroll
                for (int r = 0; r < 4; ++r) {
                    float bm = (EPI == EPI_BIASM) ? bias[mb + r] : bv;
                    C[(long)(mb + r) * ldC + n] = __float2bfloat16(acc[i][j][r] + bm);
                }
            }
        }
    } else if constexpr (EPI == EPI_CAUCHY) {
        float* C = (float*)Cv + (long)bz * sCb;
        const float* rN = rowN + (long)bz * M;
        const float* cN = colN + (long)bz * N;
        #pragma unroll
        for (int j = 0; j < 4; ++j) {
            int n = n0 + wn * 64 + j * 16 + l15;
            float cn = cN[n];
            #pragma unroll
            for (int i = 0; i < 4; ++i) {
                int mb = m0 + wm * 64 + i * 16 + quad * 4;
                #pragma unroll
                for (int r = 0; r < 4; ++r) {
                    int m = mb + r;
                    float g = acc[i][j][r];
                    float ratio = (g * g) / (rN[m] * cn);
                    float o = __powf(ratio, P_EXP) - ((m == n) ? 1.f : 0.f);
                    float v = 0.5f - 0.5f * __cosf(PI_F * o);
                    C[(long)m * ldC + n] = fmaxf(v, 0.f);
                }
            }
        }
    } else { // EPI_RESID
        float* C = (float*)Cv + (long)bz * sCb;
        const float* Rs = resid + (long)bz * sRb;
        #pragma unroll
        for (int j = 0; j < 4; ++j) {
            int n = n0 + wn * 64 + j * 16 + l15;
            #pragma unroll
            for (int i = 0; i < 4; ++i) {
                int mb = m0 + wm * 64 + i * 16 + quad * 4;
                #pragma unroll
                for (int r = 0; r < 4; ++r) {
                    int m = mb + r;
                    C[(long)m * ldC + n] = (acc[i][j][r] + Rs[(long)m * ldC + n]) * 0.5f;
                }
            }
        }
    }
}

// ---------------------------------------------------------------------------
// Transpose-cast: in (nb, R, C) [TI = float or bf16] -> out (nb, C, R) bf16.
// ---------------------------------------------------------------------------
template<typename TI>
__global__ __launch_bounds__(256)
void transpose_cast(const TI* __restrict__ in, bf* __restrict__ outp, int R, int C)
{
    __shared__ float tile[32][33];
    long base = (long)blockIdx.z * R * C;
    int r0 = blockIdx.y * 32, c0 = blockIdx.x * 32;
    int tx = threadIdx.x & 31, ty = threadIdx.x >> 5;
    #pragma unroll
    for (int i = 0; i < 4; ++i)
        tile[ty + 8 * i][tx] = (float)in[base + (long)(r0 + ty + 8 * i) * C + c0 + tx];
    __syncthreads();
    #pragma unroll
    for (int i = 0; i < 4; ++i)
        outp[base + (long)(c0 + ty + 8 * i) * R + r0 + tx] = __float2bfloat16(tile[tx][ty + 8 * i]);
}

// Flat fp32 -> bf16 cast
__global__ __launch_bounds__(256)
void cast_bf(const float* __restrict__ in, bf* __restrict__ outp, long n)
{
    long i = (long)blockIdx.x * 256 + threadIdx.x;
    if (i < n) outp[i] = __float2bfloat16(in[i]);
}

// Row sum-of-squares over contiguous last dim (bf16 in, fp32 out)
__global__ __launch_bounds__(256)
void rowsumsq(const bf* __restrict__ v, float* __restrict__ outp, int ncols)
{
    long row = blockIdx.x;
    const bf* p = v + row * (long)ncols;
    float s = 0.f;
    for (int c = threadIdx.x; c < ncols; c += 256) { float t = (float)p[c]; s += t * t; }
    __shared__ float red[256];
    red[threadIdx.x] = s; __syncthreads();
    for (int off = 128; off > 0; off >>= 1) {
        if (threadIdx.x < off) red[threadIdx.x] += red[threadIdx.x + off];
        __syncthreads();
    }
    if (threadIdx.x == 0) outp[row] = red[0];
}

// matvec: out[o] = sum_i W[o][i]*v[i] + c[o]   (fp32, tiny)
__global__ __launch_bounds__(256)
void matvec_bias(const float* __restrict__ W, const float* __restrict__ v,
                 const float* __restrict__ c, float* __restrict__ outp, int n)
{
    int o = blockIdx.x;
    const float* row = W + (long)o * n;
    float s = 0.f;
    for (int i = threadIdx.x; i < n; i += 256) s += row[i] * v[i];
    __shared__ float red[256];
    red[threadIdx.x] = s; __syncthreads();
    for (int off = 128; off > 0; off >>= 1) {
        if (threadIdx.x < off) red[threadIdx.x] += red[threadIdx.x + off];
        __syncthreads();
    }
    if (threadIdx.x == 0) outp[o] = red[0] + c[o];
}

// bf16 RNE pack (finite values only)
static __device__ inline unsigned short f2bf_rne(float f)
{
    union { float f; unsigned u; } uf; uf.f = f;
    unsigned r = uf.u + 0x7fff + ((uf.u >> 16) & 1);
    return (unsigned short)(r >> 16);
}

// ---------------------------------------------------------------------------
// Row softmax, fp32 in (rows x M contiguous) -> bf16 out. One block per row,
// whole row register-cached: one global read + one bf16 write.
// ---------------------------------------------------------------------------
template<int M>
__global__ __launch_bounds__(256)
void softmax_row_bf16(const float* __restrict__ G, bf* __restrict__ outp)
{
    constexpr int NV = M / 1024;    // float4s per thread
    long row = blockIdx.x;
    const float4* p = (const float4*)(G + row * (long)M);
    ushort4* q = (ushort4*)(outp + row * (long)M);
    __shared__ float red[256];

    float4 v[NV];
    float lmax = -3.4e38f;
    #pragma unroll
    for (int k = 0; k < NV; ++k) {
        v[k] = p[threadIdx.x + 256 * k];
        lmax = fmaxf(lmax, fmaxf(fmaxf(v[k].x, v[k].y), fmaxf(v[k].z, v[k].w)));
    }
    red[threadIdx.x] = lmax; __syncthreads();
    for (int off = 128; off > 0; off >>= 1) {
        if (threadIdx.x < off) red[threadIdx.x] = fmaxf(red[threadIdx.x], red[threadIdx.x + off]);
        __syncthreads();
    }
    float mm = red[0]; __syncthreads();

    float s = 0.f;
    #pragma unroll
    for (int k = 0; k < NV; ++k) {
        v[k].x = __expf(v[k].x - mm); v[k].y = __expf(v[k].y - mm);
        v[k].z = __expf(v[k].z - mm); v[k].w = __expf(v[k].w - mm);
        s += (v[k].x + v[k].y) + (v[k].z + v[k].w);
    }
    red[threadIdx.x] = s; __syncthreads();
    for (int off = 128; off > 0; off >>= 1) {
        if (threadIdx.x < off) red[threadIdx.x] += red[threadIdx.x + off];
        __syncthreads();
    }
    float inv = 1.f / red[0];
    #pragma unroll
    for (int k = 0; k < NV; ++k) {
        ushort4 o;
        o.x = f2bf_rne(v[k].x * inv); o.y = f2bf_rne(v[k].y * inv);
        o.z = f2bf_rne(v[k].z * inv); o.w = f2bf_rne(v[k].w * inv);
        q[threadIdx.x + 256 * k] = o;
    }
}

// ---------------------------------------------------------------------------
// Host-side GEMM dispatch
// ---------------------------------------------------------------------------
static void glaunch(hipStream_t st, int epi,
                    const bf* A, long sAb, int ldA,
                    const bf* Bt, long sBb, int ldB,
                    void* C, long sCb, int ldC,
                    const float* bias, const float* rowN, const float* colN,
                    const float* resid, long sRb,
                    int M, int N, int K, int nb)
{
    dim3 g(N / 128, M / 128, nb), blk(256);
    const short* As = (const short*)A;
    const short* Bs = (const short*)Bt;
    switch (epi) {
    case EPI_BIAS:   gemm_nt<EPI_BIAS>  <<<g, blk, 0, st>>>(As, sAb, ldA, Bs, sBb, ldB, C, sCb, ldC, bias, rowN, colN, resid, sRb, M, N, K); break;
    case EPI_BIASM:  gemm_nt<EPI_BIASM> <<<g, blk, 0, st>>>(As, sAb, ldA, Bs, sBb, ldB, C, sCb, ldC, bias, rowN, colN, resid, sRb, M, N, K); break;
    case EPI_PLAIN:  gemm_nt<EPI_PLAIN> <<<g, blk, 0, st>>>(As, sAb, ldA, Bs, sBb, ldB, C, sCb, ldC, bias, rowN, colN, resid, sRb, M, N, K); break;
    case EPI_CAUCHY: gemm_nt<EPI_CAUCHY><<<g, blk, 0, st>>>(As, sAb, ldA, Bs, sBb, ldB, C, sCb, ldC, bias, rowN, colN, resid, sRb, M, N, K); break;
    default:         gemm_nt<EPI_RESID> <<<g, blk, 0, st>>>(As, sAb, ldA, Bs, sBb, ldB, C, sCb, ldC, bias, rowN, colN, resid, sRb, M, N, K); break;
    }
}

extern "C" void kernel_launch(void* const* d_in, const int* in_sizes, int n_in,
                              void* d_out, int out_size, void* d_ws, size_t ws_size,
                              hipStream_t stream)
{
    const float* x = (const float*)d_in[0];
    float* out = (float*)d_out;

    // Arena (bytes). Total 184,766,464 (proven safe in earlier rounds).
    uint8_t* wsb = (uint8_t*)d_ws;
    if (ws_size < 184766464u) return;

    bf*    x_t    = (bf*)(wsb + 0);              // (B,L,D) bf16; later Gl-pair fp32
    bf*    dscore = (bf*)(wsb + 33554432);       // (B,D,D) bf16; later lscore^T pair
    bf*    Weff   = (bf*)(wsb + 50331648);       // 4 x (D,D) bf16
    float* beff   = (float*)(wsb + 58720256);    // 4 x D fp32
    float* b01    = (float*)(wsb + 58736640);    // D fp32
    float* ns_d   = (float*)(wsb + 58740736);    // norms
    float* nc_d   = ns_d + (long)Bn * Dn;
    float* ns_l   = nc_d + (long)Bn * Dn;
    float* nc_l   = ns_l + (long)Bn * Ln;
    uint8_t* R0   = wsb + 58937344;              // 25,165,824 reuse region
    bf*    S0     = (bf*)(wsb + 84103168);       // 33,554,432 each
    bf*    S1     = (bf*)(wsb + 117657600);
    bf*    S2     = (bf*)(wsb + 151212032);

    // Compose-phase staging inside S0/S1 (free until channel branch)
    bf* W1b4 = S0;                 // 4 x DDm bf16
    bf* W2b4 = S0 + 4 * DDm;
    bf* W0t4 = S0 + 8 * DDm;
    bf* Zb4  = S1;
    bf* Zt4  = S1 + 4 * DDm;

    // ---- x transpose-cast: (B,D,L) f32 -> (B,L,D) bf16 ----
    transpose_cast<float><<<dim3(Ln / 32, Dn / 32, Bn), 256, 0, stream>>>(x, x_t, Dn, Ln);

    // ---- stage all four MLPs' weights, then batched compose GEMMs ----
    for (int k = 0; k < 4; ++k) {
        const float* Wk = (const float*)d_in[1 + 2 * k];
        const float* bk = (const float*)d_in[2 + 2 * k];
        cast_bf<<<dim3((unsigned)(DDm / 256)), 256, 0, stream>>>(Wk + DDm,     W1b4 + (long)k * DDm, DDm);
        cast_bf<<<dim3((unsigned)(DDm / 256)), 256, 0, stream>>>(Wk + 2 * DDm, W2b4 + (long)k * DDm, DDm);
        transpose_cast<float><<<dim3(Dn / 32, Dn / 32, 1), 256, 0, stream>>>(Wk, W0t4 + (long)k * DDm, Dn, Dn);
        matvec_bias<<<dim3(Dn), 256, 0, stream>>>(Wk + DDm,     bk,  bk + Dn,     b01,                 Dn);
        matvec_bias<<<dim3(Dn), 256, 0, stream>>>(Wk + 2 * DDm, b01, bk + 2 * Dn, beff + (long)k * Dn, Dn);
    }
    // Z = W1*W0 (nb=4), Weff = W2*Z (nb=4)
    glaunch(stream, EPI_PLAIN, W1b4, DDm, Dn, W0t4, DDm, Dn, Zb4, DDm, Dn,
            nullptr, nullptr, nullptr, nullptr, 0, Dn, Dn, Dn, 4);
    transpose_cast<bf><<<dim3(Dn / 32, Dn / 32, 4), 256, 0, stream>>>(Zb4, Zt4, Dn, Dn);
    glaunch(stream, EPI_PLAIN, W2b4, DDm, Dn, Zt4, DDm, Dn, Weff, DDm, Dn,
            nullptr, nullptr, nullptr, nullptr, 0, Dn, Dn, Dn, 4);

    // ---- channel branch ----
    // dsx (B,D,L) = NT(A=Weff1, Bt=x_t) + bias[m]  -> S0 (direct, no transpose)
    glaunch(stream, EPI_BIASM, Weff, 0, Dn, x_t, DL, Dn, S0, DL, Ln,
            beff, nullptr, nullptr, nullptr, 0, Dn, Ln, Dn, Bn);
    glaunch(stream, EPI_BIASM, Weff + DDm, 0, Dn, x_t, DL, Dn, S2, DL, Ln,
            beff + Dn, nullptr, nullptr, nullptr, 0, Dn, Ln, Dn, Bn);   // dcx -> S2

    rowsumsq<<<dim3(Bn * Dn), 256, 0, stream>>>(S0, ns_d, Ln);
    rowsumsq<<<dim3(Bn * Dn), 256, 0, stream>>>(S2, nc_d, Ln);

    // Gd^T fp32 = cauchy(dcx @ dsx^T) @ S1  (rowN/colN swapped for transpose)
    glaunch(stream, EPI_CAUCHY, S2, DL, Ln, S0, DL, Ln, (float*)S1, DDm, Dn,
            nullptr, nc_d, ns_d, nullptr, 0, Dn, Dn, Ln, Bn);
    // softmax over original axis 1 == row softmax of Gd^T -> dscore_t (R0)
    softmax_row_bf16<Dn><<<dim3(Bn * Dn), 256, 0, stream>>>((float*)S1, (bf*)R0);
    transpose_cast<bf><<<dim3(Dn / 32, Dn / 32, Bn), 256, 0, stream>>>((bf*)R0, dscore, Dn, Dn);

    // ---- token branch ----
    glaunch(stream, EPI_BIAS, x_t, DL, Dn, Weff + 2 * DDm, 0, Dn, S0, DL, Dn,
            beff + 2 * Dn, nullptr, nullptr, nullptr, 0, Ln, Dn, Dn, Bn);   // lsx_t -> S0
    glaunch(stream, EPI_BIAS, x_t, DL, Dn, Weff + 3 * DDm, 0, Dn, S2, DL, Dn,
            beff + 3 * Dn, nullptr, nullptr, nullptr, 0, Ln, Dn, Dn, Bn);   // lcx_t -> S2

    rowsumsq<<<dim3(Bn * Ln), 256, 0, stream>>>(S0, ns_l, Dn);
    rowsumsq<<<dim3(Bn * Ln), 256, 0, stream>>>(S2, nc_l, Dn);

    // t1 = dscore @ x, all 8 batches -> S1 bf16 (x_t free after this)
    glaunch(stream, EPI_PLAIN, dscore, DDm, Dn, x_t, DL, Dn, S1, DL, Ln,
            nullptr, nullptr, nullptr, nullptr, 0, Dn, Ln, Dn, Bn);

    // ---- token score + apply, in batch pairs ----
    float* Gp   = (float*)x_t;      // 2 x LLm fp32 = 33.5 MB (x_t slot)
    bf*    lscp = (bf*)R0;          // lscore pair, normal layout
    bf*    lsct = dscore;           // lscore^T pair (dscore slot free after t1)
    for (int pb = 0; pb < 4; ++pb) {
        long bo = 2L * pb;
        // Gl pair fp32 normal layout = cauchy(lsx^T @ lcx)
        glaunch(stream, EPI_CAUCHY, S0 + bo * DL, DL, Dn, S2 + bo * DL, DL, Dn,
                Gp, LLm, Ln, nullptr, ns_l + bo * Ln, nc_l + bo * Ln, nullptr, 0,
                Ln, Ln, Dn, 2);
        // softmax over axis 2 == row softmax -> lscore pair, then transpose -> Bt operand
        softmax_row_bf16<Ln><<<dim3(2 * Ln), 256, 0, stream>>>(Gp, lscp);
        transpose_cast<bf><<<dim3(Ln / 32, Ln / 32, 2), 256, 0, stream>>>(lscp, lsct, Ln, Ln);
        // out = (t1 @ lscore + x) / 2
        glaunch(stream, EPI_RESID, S1 + bo * DL, DL, Ln, lsct, LLm, Ln,
                out + bo * DL, DL, Ln, nullptr, nullptr, nullptr, x + bo * DL, DL,
                Dn, Ln, Ln, 2);
    }
}

// Round 5
// 1052.476 us; speedup vs baseline: 12.3489x; 1.4371x over previous
//
#include <hip/hip_runtime.h>
#include <hip/hip_bf16.h>
#include <math.h>

// Problem constants
static constexpr int  Bn = 8, Dn = 1024, Ln = 2048;
static constexpr long DL  = (long)Dn * Ln;
static constexpr long DDm = (long)Dn * Dn;
static constexpr long LLm = (long)Ln * Ln;
static constexpr float P_EXP = 1.01005016708416805754f; // exp(0.01)
static constexpr float PI_F  = 3.14159265358979323846f;

using bf = __hip_bfloat16;
typedef short s16x8 __attribute__((ext_vector_type(8)));   // 8 bf16 = 4 VGPRs (MFMA A/B frag)
typedef float f32x4 __attribute__((ext_vector_type(4)));   // MFMA C/D frag

#define GPTR(x) ((const __attribute__((address_space(1))) void*)(x))
#define LPTR(x) ((__attribute__((address_space(3))) void*)(x))

enum { EPI_BIAS = 0, EPI_PLAIN = 1, EPI_CAUCHY = 2, EPI_RESID = 3, EPI_BIASM = 4, EPI_CAUCHYB = 5 };

// bf16 RNE pack (finite values only)
static __device__ inline unsigned short f2bf_rne(float f)
{
    union { float f; unsigned u; } uf; uf.f = f;
    unsigned r = uf.u + 0x7fff + ((uf.u >> 16) & 1);
    return (unsigned short)(r >> 16);
}
static __device__ inline float bf2f(unsigned short s)
{
    union { unsigned u; float f; } uf; uf.u = ((unsigned)s) << 16;
    return uf.f;
}

struct P4 { const float* p[4]; };

// ---------------------------------------------------------------------------
// NT bf16 MFMA GEMM: C[b,m,n] = sum_k A[b,m,k] * Bt[b,n,k]   (both k-contig)
// 128x128 tile, BK=32, 256 threads (4 waves, 2x2 of 64x64 wave tiles),
// global_load_lds width-16 staging, swizzled LDS k-chunks.
// launch_bounds(256,4): cap VGPR at 128 -> 4 resident blocks/CU.
// ---------------------------------------------------------------------------
template<int EPI>
__global__ __launch_bounds__(256, 4)
void gemm_nt(const short* __restrict__ A, long sAb, int ldA,
             const short* __restrict__ Bt, long sBb, int ldB,
             void* __restrict__ Cv, long sCb, int ldC,
             const float* __restrict__ bias,
             const float* __restrict__ rowN, const float* __restrict__ colN,
             const float* __restrict__ resid, long sRb,
             int M, int N, int K)
{
    __shared__ short As[128 * 32];   // row-major, 32 bf16 per row, k-chunk swizzled
    __shared__ short Bs[128 * 32];

    const int tid  = threadIdx.x;
    const int lane = tid & 63;
    const int w    = tid >> 6;           // wave 0..3
    const int wm   = w >> 1, wn = w & 1; // 2x2 wave grid
    const int m0   = blockIdx.y * 128;
    const int n0   = blockIdx.x * 128;
    const int bz   = blockIdx.z;

    const short* Ab = A  + (long)bz * sAb;
    const short* Bb = Bt + (long)bz * sBb;

    const int srow = lane >> 2;                                  // 0..15 row within 16-row chunk
    const int kc   = ((lane & 3) + 4 - ((lane >> 3) & 3)) & 3;   // swizzled global k-chunk
    const int quad = lane >> 4;
    const int l15  = lane & 15;

    // LDS read offsets (shorts) for the 4 A / 4 B fragments
    int aoff[4], boff[4];
    #pragma unroll
    for (int i = 0; i < 4; ++i) {
        int rA = wm * 64 + i * 16 + l15;
        aoff[i] = rA * 32 + (((quad + (rA >> 1)) & 3) << 3);
        int rB = wn * 64 + i * 16 + l15;
        boff[i] = rB * 32 + (((quad + (rB >> 1)) & 3) << 3);
    }

    // staging: wave w owns 1KB chunks {2w, 2w+1} of both A and B tiles
    const int  ca0 = 2 * w;
    const long gA0 = (long)(m0 + ca0 * 16 + srow)       * ldA + kc * 8;
    const long gA1 = (long)(m0 + (ca0 + 1) * 16 + srow) * ldA + kc * 8;
    const long gB0 = (long)(n0 + ca0 * 16 + srow)       * ldB + kc * 8;
    const long gB1 = (long)(n0 + (ca0 + 1) * 16 + srow) * ldB + kc * 8;
    short* lA0 = As + ca0 * 512;
    short* lA1 = As + ca0 * 512 + 512;
    short* lB0 = Bs + ca0 * 512;
    short* lB1 = Bs + ca0 * 512 + 512;

    f32x4 acc[4][4] = {};

    for (int k0 = 0; k0 < K; k0 += 32) {
        __builtin_amdgcn_global_load_lds(GPTR(Ab + gA0 + k0), LPTR(lA0), 16, 0, 0);
        __builtin_amdgcn_global_load_lds(GPTR(Ab + gA1 + k0), LPTR(lA1), 16, 0, 0);
        __builtin_amdgcn_global_load_lds(GPTR(Bb + gB0 + k0), LPTR(lB0), 16, 0, 0);
        __builtin_amdgcn_global_load_lds(GPTR(Bb + gB1 + k0), LPTR(lB1), 16, 0, 0);
        __syncthreads();

        s16x8 af[4], bfr[4];
        #pragma unroll
        for (int i = 0; i < 4; ++i) af[i]  = *(const s16x8*)(As + aoff[i]);
        #pragma unroll
        for (int j = 0; j < 4; ++j) bfr[j] = *(const s16x8*)(Bs + boff[j]);
        #pragma unroll
        for (int i = 0; i < 4; ++i)
            #pragma unroll
            for (int j = 0; j < 4; ++j)
                acc[i][j] = __builtin_amdgcn_mfma_f32_16x16x32_bf16(af[i], bfr[j], acc[i][j], 0, 0, 0);
        __syncthreads();
    }

    // Epilogue. C/D layout: col = lane&15, row = quad*4 + r within each 16x16.
    if constexpr (EPI == EPI_BIAS || EPI == EPI_PLAIN || EPI == EPI_BIASM) {
        bf* C = (bf*)Cv + (long)bz * sCb;
        #pragma unroll
        for (int j = 0; j < 4; ++j) {
            int n = n0 + wn * 64 + j * 16 + l15;
            float bv = (EPI == EPI_BIAS) ? bias[n] : 0.f;
            #pragma unroll
            for (int i = 0; i < 4; ++i) {
                int mb = m0 + wm * 64 + i * 16 + quad * 4;
                #pragma unroll
                for (int r = 0; r < 4; ++r) {
                    float bm = (EPI == EPI_BIASM) ? bias[mb + r] : bv;
                    C[(long)(mb + r) * ldC + n] = __float2bfloat16(acc[i][j][r] + bm);
                }
            }
        }
    } else if constexpr (EPI == EPI_CAUCHY || EPI == EPI_CAUCHYB) {
        const float* rN = rowN + (long)bz * M;
        const float* cN = colN + (long)bz * N;
        #pragma unroll
        for (int j = 0; j < 4; ++j) {
            int n = n0 + wn * 64 + j * 16 + l15;
            float cn = cN[n];
            #pragma unroll
            for (int i = 0; i < 4; ++i) {
                int mb = m0 + wm * 64 + i * 16 + quad * 4;
                #pragma unroll
                for (int r = 0; r < 4; ++r) {
                    int m = mb + r;
                    float g = acc[i][j][r];
                    float ratio = (g * g) / (rN[m] * cn);
                    float o = __powf(ratio, P_EXP) - ((m == n) ? 1.f : 0.f);
                    float v = fmaxf(0.5f - 0.5f * __cosf(PI_F * o), 0.f);
                    if constexpr (EPI == EPI_CAUCHY)
                        ((float*)Cv + (long)bz * sCb)[(long)m * ldC + n] = v;
                    else
                        ((unsigned short*)Cv + (long)bz * sCb)[(long)m * ldC + n] = f2bf_rne(v);
                }
            }
        }
    } else { // EPI_RESID
        float* C = (float*)Cv + (long)bz * sCb;
        const float* Rs = resid + (long)bz * sRb;
        #pragma unroll
        for (int j = 0; j < 4; ++j) {
            int n = n0 + wn * 64 + j * 16 + l15;
            #pragma unroll
            for (int i = 0; i < 4; ++i) {
                int mb = m0 + wm * 64 + i * 16 + quad * 4;
                #pragma unroll
                for (int r = 0; r < 4; ++r) {
                    int m = mb + r;
                    C[(long)m * ldC + n] = (acc[i][j][r] + Rs[(long)m * ldC + n]) * 0.5f;
                }
            }
        }
    }
}

// ---------------------------------------------------------------------------
// Transpose-cast: in (nb, R, C) [TI = float or bf16] -> out (nb, C, R) bf16.
// ---------------------------------------------------------------------------
template<typename TI>
__global__ __launch_bounds__(256)
void transpose_cast(const TI* __restrict__ in, bf* __restrict__ outp, int R, int C)
{
    __shared__ float tile[32][33];
    long base = (long)blockIdx.z * R * C;
    int r0 = blockIdx.y * 32, c0 = blockIdx.x * 32;
    int tx = threadIdx.x & 31, ty = threadIdx.x >> 5;
    #pragma unroll
    for (int i = 0; i < 4; ++i)
        tile[ty + 8 * i][tx] = (float)in[base + (long)(r0 + ty + 8 * i) * C + c0 + tx];
    __syncthreads();
    #pragma unroll
    for (int i = 0; i < 4; ++i)
        outp[base + (long)(c0 + ty + 8 * i) * R + r0 + tx] = __float2bfloat16(tile[tx][ty + 8 * i]);
}

// Batched weight cast: W1b4/W2b4[k] = bf16(Wk[layer*DDm]), layer in {1,2}
__global__ __launch_bounds__(256)
void cast_w12(P4 w, bf* __restrict__ w1b4, bf* __restrict__ w2b4)
{
    long i = (long)blockIdx.x * 256 + threadIdx.x;   // over DDm/4
    int layer = blockIdx.y, k = blockIdx.z;
    const float4* src = (const float4*)(w.p[k] + (long)(layer + 1) * DDm);
    ushort4* dst = (ushort4*)((layer ? w2b4 : w1b4) + (long)k * DDm);
    float4 v = src[i];
    ushort4 o; o.x = f2bf_rne(v.x); o.y = f2bf_rne(v.y); o.z = f2bf_rne(v.z); o.w = f2bf_rne(v.w);
    dst[i] = o;
}

// Batched W0 transpose-cast: w0t4[k] = bf16(Wk[0]^T)
__global__ __launch_bounds__(256)
void transpose_w0(P4 w, bf* __restrict__ w0t4)
{
    __shared__ float tile[32][33];
    int k = blockIdx.z;
    const float* in = w.p[k];
    bf* outp = w0t4 + (long)k * DDm;
    int r0 = blockIdx.y * 32, c0 = blockIdx.x * 32;
    int tx = threadIdx.x & 31, ty = threadIdx.x >> 5;
    #pragma unroll
    for (int i = 0; i < 4; ++i)
        tile[ty + 8 * i][tx] = in[(long)(r0 + ty + 8 * i) * Dn + c0 + tx];
    __syncthreads();
    #pragma unroll
    for (int i = 0; i < 4; ++i)
        outp[(long)(c0 + ty + 8 * i) * Dn + r0 + tx] = __float2bfloat16(tile[tx][ty + 8 * i]);
}

// Batched bias compose. stage 0: out4[k]=W1_k*b0_k+b1_k; stage 1: out4[k]=W2_k*vin4[k]+b2_k
__global__ __launch_bounds__(256)
void matvec4(P4 w, P4 b, const float* __restrict__ vin4, float* __restrict__ out4, int stage)
{
    int k = blockIdx.y, o = blockIdx.x;
    const float* W = w.p[k] + (long)(stage ? 2 : 1) * DDm + (long)o * Dn;
    const float* v = stage ? (vin4 + (long)k * Dn) : b.p[k];
    const float* c = b.p[k] + (long)(stage ? 2 : 1) * Dn;
    float s = 0.f;
    for (int i = threadIdx.x; i < Dn; i += 256) s += W[i] * v[i];
    __shared__ float red[256];
    red[threadIdx.x] = s; __syncthreads();
    for (int off = 128; off > 0; off >>= 1) {
        if (threadIdx.x < off) red[threadIdx.x] += red[threadIdx.x + off];
        __syncthreads();
    }
    if (threadIdx.x == 0) out4[(long)k * Dn + o] = red[0] + c[o];
}

// Strided row sum-of-squares (bf16 in, fp32 out), vectorized ushort4.
// row -> b = row / rpb, r = row % rpb; base = b*bstride + r*ld; ncols in {1024,2048}
__global__ __launch_bounds__(256)
void rowsumsq_s(const unsigned short* __restrict__ v, float* __restrict__ outp,
                int ncols, int ld, int rpb, long bstride)
{
    int row = blockIdx.x;
    int b = row / rpb, r = row % rpb;
    const unsigned short* p = v + (long)b * bstride + (long)r * ld;
    float s = 0.f;
    for (int c4 = threadIdx.x * 4; c4 < ncols; c4 += 1024) {
        ushort4 u = *(const ushort4*)(p + c4);
        float a0 = bf2f(u.x), a1 = bf2f(u.y), a2 = bf2f(u.z), a3 = bf2f(u.w);
        s += a0 * a0 + a1 * a1 + a2 * a2 + a3 * a3;
    }
    __shared__ float red[256];
    red[threadIdx.x] = s; __syncthreads();
    for (int off = 128; off > 0; off >>= 1) {
        if (threadIdx.x < off) red[threadIdx.x] += red[threadIdx.x + off];
        __syncthreads();
    }
    if (threadIdx.x == 0) outp[row] = red[0];
}

// ---------------------------------------------------------------------------
// Row softmax, fp32 in (rows x M contiguous) -> bf16 out (channel branch).
// ---------------------------------------------------------------------------
template<int M>
__global__ __launch_bounds__(256)
void softmax_row_bf16(const float* __restrict__ G, bf* __restrict__ outp)
{
    constexpr int NV = M / 1024;    // float4s per thread
    long row = blockIdx.x;
    const float4* p = (const float4*)(G + row * (long)M);
    ushort4* q = (ushort4*)(outp + row * (long)M);
    __shared__ float red[256];

    float4 v[NV];
    float lmax = -3.4e38f;
    #pragma unroll
    for (int k = 0; k < NV; ++k) {
        v[k] = p[threadIdx.x + 256 * k];
        lmax = fmaxf(lmax, fmaxf(fmaxf(v[k].x, v[k].y), fmaxf(v[k].z, v[k].w)));
    }
    red[threadIdx.x] = lmax; __syncthreads();
    for (int off = 128; off > 0; off >>= 1) {
        if (threadIdx.x < off) red[threadIdx.x] = fmaxf(red[threadIdx.x], red[threadIdx.x + off]);
        __syncthreads();
    }
    float mm = red[0]; __syncthreads();

    float s = 0.f;
    #pragma unroll
    for (int k = 0; k < NV; ++k) {
        v[k].x = __expf(v[k].x - mm); v[k].y = __expf(v[k].y - mm);
        v[k].z = __expf(v[k].z - mm); v[k].w = __expf(v[k].w - mm);
        s += (v[k].x + v[k].y) + (v[k].z + v[k].w);
    }
    red[threadIdx.x] = s; __syncthreads();
    for (int off = 128; off > 0; off >>= 1) {
        if (threadIdx.x < off) red[threadIdx.x] += red[threadIdx.x + off];
        __syncthreads();
    }
    float inv = 1.f / red[0];
    #pragma unroll
    for (int k = 0; k < NV; ++k) {
        ushort4 o;
        o.x = f2bf_rne(v[k].x * inv); o.y = f2bf_rne(v[k].y * inv);
        o.z = f2bf_rne(v[k].z * inv); o.w = f2bf_rne(v[k].w * inv);
        q[threadIdx.x + 256 * k] = o;
    }
}

// In-place row softmax on bf16, M = Ln (2048): 8 shorts/thread, one 16B ld/st.
__global__ __launch_bounds__(256)
void softmax_ip_bf16(unsigned short* __restrict__ G)
{
    long row = blockIdx.x;
    s16x8* p = (s16x8*)(G + row * (long)Ln);
    s16x8 raw = p[threadIdx.x];
    float v[8];
    #pragma unroll
    for (int j = 0; j < 8; ++j) v[j] = bf2f((unsigned short)raw[j]);

    __shared__ float red[256];
    float lmax = -3.4e38f;
    #pragma unroll
    for (int j = 0; j < 8; ++j) lmax = fmaxf(lmax, v[j]);
    red[threadIdx.x] = lmax; __syncthreads();
    for (int off = 128; off > 0; off >>= 1) {
        if (threadIdx.x < off) red[threadIdx.x] = fmaxf(red[threadIdx.x], red[threadIdx.x + off]);
        __syncthreads();
    }
    float mm = red[0]; __syncthreads();

    float s = 0.f;
    #pragma unroll
    for (int j = 0; j < 8; ++j) { v[j] = __expf(v[j] - mm); s += v[j]; }
    red[threadIdx.x] = s; __syncthreads();
    for (int off = 128; off > 0; off >>= 1) {
        if (threadIdx.x < off) red[threadIdx.x] += red[threadIdx.x + off];
        __syncthreads();
    }
    float inv = 1.f / red[0];
    s16x8 o;
    #pragma unroll
    for (int j = 0; j < 8; ++j) o[j] = (short)f2bf_rne(v[j] * inv);
    p[threadIdx.x] = o;
}

// In-place square transpose of (nb, Ln, Ln) bf16, 32x32 tile pairs.
__global__ __launch_bounds__(256)
void transpose_ip(unsigned short* __restrict__ G)
{
    int bi = blockIdx.y, bj = blockIdx.x;
    if (bj < bi) return;
    long base = (long)blockIdx.z * LLm;
    __shared__ unsigned short t1[32][33], t2[32][33];
    int tx = threadIdx.x & 31, ty = threadIdx.x >> 5;
    int r0 = bi * 32, c0 = bj * 32;
    #pragma unroll
    for (int i = 0; i < 4; ++i)
        t1[ty + 8 * i][tx] = G[base + (long)(r0 + ty + 8 * i) * Ln + c0 + tx];
    if (bi != bj) {
        #pragma unroll
        for (int i = 0; i < 4; ++i)
            t2[ty + 8 * i][tx] = G[base + (long)(c0 + ty + 8 * i) * Ln + r0 + tx];
    }
    __syncthreads();
    #pragma unroll
    for (int i = 0; i < 4; ++i)
        G[base + (long)(c0 + ty + 8 * i) * Ln + r0 + tx] = t1[tx][ty + 8 * i];
    if (bi != bj) {
        #pragma unroll
        for (int i = 0; i < 4; ++i)
            G[base + (long)(r0 + ty + 8 * i) * Ln + c0 + tx] = t2[tx][ty + 8 * i];
    }
}

// ---------------------------------------------------------------------------
// Host-side GEMM dispatch
// ---------------------------------------------------------------------------
static void glaunch(hipStream_t st, int epi,
                    const bf* A, long sAb, int ldA,
                    const bf* Bt, long sBb, int ldB,
                    void* C, long sCb, int ldC,
                    const float* bias, const float* rowN, const float* colN,
                    const float* resid, long sRb,
                    int M, int N, int K, int nb)
{
    dim3 g(N / 128, M / 128, nb), blk(256);
    const short* As = (const short*)A;
    const short* Bs = (const short*)Bt;
    switch (epi) {
    case EPI_BIAS:    gemm_nt<EPI_BIAS>   <<<g, blk, 0, st>>>(As, sAb, ldA, Bs, sBb, ldB, C, sCb, ldC, bias, rowN, colN, resid, sRb, M, N, K); break;
    case EPI_BIASM:   gemm_nt<EPI_BIASM>  <<<g, blk, 0, st>>>(As, sAb, ldA, Bs, sBb, ldB, C, sCb, ldC, bias, rowN, colN, resid, sRb, M, N, K); break;
    case EPI_PLAIN:   gemm_nt<EPI_PLAIN>  <<<g, blk, 0, st>>>(As, sAb, ldA, Bs, sBb, ldB, C, sCb, ldC, bias, rowN, colN, resid, sRb, M, N, K); break;
    case EPI_CAUCHY:  gemm_nt<EPI_CAUCHY> <<<g, blk, 0, st>>>(As, sAb, ldA, Bs, sBb, ldB, C, sCb, ldC, bias, rowN, colN, resid, sRb, M, N, K); break;
    case EPI_CAUCHYB: gemm_nt<EPI_CAUCHYB><<<g, blk, 0, st>>>(As, sAb, ldA, Bs, sBb, ldB, C, sCb, ldC, bias, rowN, colN, resid, sRb, M, N, K); break;
    default:          gemm_nt<EPI_RESID>  <<<g, blk, 0, st>>>(As, sAb, ldA, Bs, sBb, ldB, C, sCb, ldC, bias, rowN, colN, resid, sRb, M, N, K); break;
    }
}

extern "C" void kernel_launch(void* const* d_in, const int* in_sizes, int n_in,
                              void* d_out, int out_size, void* d_ws, size_t ws_size,
                              hipStream_t stream)
{
    const float* x = (const float*)d_in[0];
    float* out = (float*)d_out;

    // Arena (bytes), total 159,600,640:
    //   x_t   [0,          33,554,432)  (B,L,D) bf16; token phase: Gl half (4 x L x L bf16)
    //   dscore[33,554,432, 50,331,648)  (B,D,D) bf16
    //   Weff  [50,331,648, 58,720,256)  4 x (D,D) bf16
    //   beff  [58,720,256, +16K) b01_4 [+16K, +32K) norms [58,752,  ...]
    //   O1    [58,937,344, 126,046,208) 67MB: compose staging / dsdc concat / dscoreT / lslc concat
    //   O2    [126,046,208,159,600,640) 33.5MB: GdT fp32 / t1 bf16
    uint8_t* wsb = (uint8_t*)d_ws;
    if (ws_size < 159600640u) return;

    bf*    x_t    = (bf*)(wsb + 0);
    bf*    dscore = (bf*)(wsb + 33554432);
    bf*    Weff   = (bf*)(wsb + 50331648);
    float* beff   = (float*)(wsb + 58720256);    // 4 x D
    float* b01_4  = (float*)(wsb + 58736640);    // 4 x D
    float* ns_d   = (float*)(wsb + 58753024);
    float* nc_d   = ns_d + (long)Bn * Dn;
    float* ns_l   = nc_d + (long)Bn * Dn;
    float* nc_l   = ns_l + (long)Bn * Ln;
    uint8_t* O1   = wsb + 58937344;              // 67,108,864
    uint8_t* O2   = wsb + 126046208;             // 33,554,432

    // O1 sub-layouts (time-disjoint)
    bf* W1b4 = (bf*)O1;                // compose staging: 5 x 4*DDm shorts = 40MB
    bf* W2b4 = W1b4 + 4 * DDm;
    bf* W0t4 = W1b4 + 8 * DDm;
    bf* Zb4  = W1b4 + 12 * DDm;
    bf* Zt4  = W1b4 + 16 * DDm;
    bf* dsdc = (bf*)O1;                // (B, 2D, L) bf16 = 67MB
    bf* dscoreT = (bf*)O1;             // (B, D, D) bf16 (after dsdc dead)
    bf* lslc = (bf*)O1;                // (B, L, 2D) bf16 = 67MB

    float* GdT = (float*)O2;           // (B, D, D) fp32
    bf*    t1  = (bf*)O2;              // (B, D, L) bf16 (after GdT dead)
    bf*    Gl  = x_t;                  // token phase: 4 x (L, L) bf16 (x_t dead)

    P4 W, Bv;
    for (int k = 0; k < 4; ++k) { W.p[k] = (const float*)d_in[1 + 2 * k]; Bv.p[k] = (const float*)d_in[2 + 2 * k]; }

    // ---- x transpose-cast: (B,D,L) f32 -> (B,L,D) bf16 ----
    transpose_cast<float><<<dim3(Ln / 32, Dn / 32, Bn), 256, 0, stream>>>(x, x_t, Dn, Ln);

    // ---- weight staging (batched) + bias compose ----
    cast_w12<<<dim3((unsigned)(DDm / 4 / 256), 2, 4), 256, 0, stream>>>(W, W1b4, W2b4);
    transpose_w0<<<dim3(Dn / 32, Dn / 32, 4), 256, 0, stream>>>(W, W0t4);
    matvec4<<<dim3(Dn, 4), 256, 0, stream>>>(W, Bv, nullptr, b01_4, 0);
    matvec4<<<dim3(Dn, 4), 256, 0, stream>>>(W, Bv, b01_4, beff, 1);

    // ---- compose Weff = W2*W1*W0 (nb=4 batched) ----
    glaunch(stream, EPI_PLAIN, W1b4, DDm, Dn, W0t4, DDm, Dn, Zb4, DDm, Dn,
            nullptr, nullptr, nullptr, nullptr, 0, Dn, Dn, Dn, 4);
    transpose_cast<bf><<<dim3(Dn / 32, Dn / 32, 4), 256, 0, stream>>>(Zb4, Zt4, Dn, Dn);
    glaunch(stream, EPI_PLAIN, W2b4, DDm, Dn, Zt4, DDm, Dn, Weff, DDm, Dn,
            nullptr, nullptr, nullptr, nullptr, 0, Dn, Dn, Dn, 4);

    // ---- channel branch: dsx||dcx in one concat GEMM (M=2048, 2048 blocks) ----
    glaunch(stream, EPI_BIASM, Weff, 0, Dn, x_t, DL, Dn, dsdc, 2 * DL, Ln,
            beff, nullptr, nullptr, nullptr, 0, 2 * Dn, Ln, Dn, Bn);

    rowsumsq_s<<<dim3(Bn * Dn), 256, 0, stream>>>((const unsigned short*)dsdc,      ns_d, Ln, Ln, Dn, 2 * DL);
    rowsumsq_s<<<dim3(Bn * Dn), 256, 0, stream>>>((const unsigned short*)(dsdc + DL), nc_d, Ln, Ln, Dn, 2 * DL);

    // GdT fp32 = cauchy(dcx @ dsx^T) (rowN/colN swapped for the transpose)
    glaunch(stream, EPI_CAUCHY, dsdc + DL, 2 * DL, Ln, dsdc, 2 * DL, Ln, GdT, DDm, Dn,
            nullptr, nc_d, ns_d, nullptr, 0, Dn, Dn, Ln, Bn);
    // softmax over original axis 1 == row softmax of GdT -> dscoreT, then transpose
    softmax_row_bf16<Dn><<<dim3(Bn * Dn), 256, 0, stream>>>(GdT, dscoreT);
    transpose_cast<bf><<<dim3(Dn / 32, Dn / 32, Bn), 256, 0, stream>>>(dscoreT, dscore, Dn, Dn);

    // ---- token branch: lsx_t||lcx_t in one concat GEMM (N=2048, 2048 blocks) ----
    glaunch(stream, EPI_BIAS, x_t, DL, Dn, Weff + 2 * DDm, 0, Dn, lslc, 2 * DL, 2 * Dn,
            beff + 2 * Dn, nullptr, nullptr, nullptr, 0, Ln, 2 * Dn, Dn, Bn);

    rowsumsq_s<<<dim3(Bn * Ln), 256, 0, stream>>>((const unsigned short*)lslc,        ns_l, Dn, 2 * Dn, Ln, 2 * DL);
    rowsumsq_s<<<dim3(Bn * Ln), 256, 0, stream>>>((const unsigned short*)(lslc + Dn), nc_l, Dn, 2 * Dn, Ln, 2 * DL);

    // t1 = dscore @ x, all 8 batches (x_t and dscore dead afterwards)
    glaunch(stream, EPI_PLAIN, dscore, DDm, Dn, x_t, DL, Dn, t1, DL, Ln,
            nullptr, nullptr, nullptr, nullptr, 0, Dn, Ln, Dn, Bn);

    // ---- token score + apply, in 4-batch halves ----
    for (int h = 0; h < 2; ++h) {
        long bo = 4L * h;
        const bf* lsx = lslc + bo * 2 * DL;
        const bf* lcx = lsx + Dn;
        // Gl half bf16 = cauchy(lsx^T @ lcx) (normal layout), 1024 blocks
        glaunch(stream, EPI_CAUCHYB, lsx, 2 * DL, 2 * Dn, lcx, 2 * DL, 2 * Dn,
                Gl, LLm, Ln, nullptr, ns_l + bo * Ln, nc_l + bo * Ln, nullptr, 0,
                Ln, Ln, Dn, 4);
        // softmax over axis 2 == row softmax, in place
        softmax_ip_bf16<<<dim3(4 * Ln), 256, 0, stream>>>((unsigned short*)Gl);
        // in-place transpose -> lscore^T (Bt operand)
        transpose_ip<<<dim3(Ln / 32, Ln / 32, 4), 256, 0, stream>>>((unsigned short*)Gl);
        // out = (t1 @ lscore + x) / 2, 512 blocks
        glaunch(stream, EPI_RESID, t1 + bo * DL, DL, Ln, Gl, LLm, Ln,
                out + bo * DL, DL, Ln, nullptr, nullptr, nullptr, x + bo * DL, DL,
                Dn, Ln, Ln, 4);
    }
}